// Round 15
// baseline (62.707 us; speedup 1.0000x reference)
//
#include <hip/hip_runtime.h>
#include <hip/hip_bf16.h>

// Poincare pairwise distance, c=1:
//   d(x,p) = acosh(1 + 2*||x-p||^2 / ((1-||x||^2)(1-||p||^2)))
// B=16384, N=4096, D=64. Output 16384x4096 f32 (256 MiB) -> write-bound.
//
// Round 15: SINGLE-GENERATION, zero-loop-barrier kernel. Grid 512 = exactly
// 2 blocks/CU resident ONCE (64KB LDS). Block = 256 emb rows x 512 protos:
// proto band (4 pre-swizzled tiles) staged to LDS once -> ONE barrier ->
// 4 tile iterations {MFMA, epilogue, store} with NO further barriers, so
// each CU's store pipe runs continuously to kernel end (prior rounds ran
// >=4 block-generations/CU; each boundary idled the store pipe during
// staging+MFMA -> the ~14us residual over the write floor).
//   - emb fragments: per-wave direct loads from fragment-ordered ws images
//     (R7 layout; no LDS, no barrier). Read once, XCD-local.
//   - proto: one 64KB slice per XCD n-band, L2-hot across its 64 blocks.

constexpr int BATCH = 16384;
constexpr int NCON  = 4096;
constexpr int DIM   = 64;
constexpr int TM    = 256;          // emb rows per block
constexpr int TNB   = 512;          // protos per block (4 tiles of 128)

// ws layout (bytes), 16B-aligned:
//   emb fragment images (R7 layout): strip = 16 rows; chunk((strip,kk,lane))
//     = strip*128 + kk*64 + lane; content = bf16 emb[strip*16+(lane&15)]
//     [kk*32+(lane>>4)*8 .. +7].   1024 strips * 2 KiB = 2 MiB.
//   proto LDS-image tiles (R6/R8/R12 layout): 128-row tiles, row-swizzled
//     k ^= (row&7)<<3.             32 tiles * 16 KiB = 512 KiB.
constexpr size_t WS_EMB   = 0;
constexpr size_t WS_PROTO = (size_t)2 << 20;
constexpr size_t WS_X2    = WS_PROTO + (512u << 10);  // f32[16384]
constexpr size_t WS_CROW  = WS_X2   + 64u * 1024;     // f32[16384]
constexpr size_t WS_P2    = WS_CROW + 64u * 1024;     // f32[4096]
constexpr size_t WS_RP    = WS_P2   + 16u * 1024;     // f32[4096]

typedef float  f32x4  __attribute__((ext_vector_type(4)));
typedef __bf16 bf16x8 __attribute__((ext_vector_type(8)));

// ---------------- pre-pass ----------------
// gid sections: [0,131072) emb fragment chunks (R7 layout),
//               [131072,163840) proto tile chunks (R6 layout),
//               [163840,180224) emb norms, [180224,184320) proto norms.
__global__ __launch_bounds__(256)
void prepass_kernel(const float* __restrict__ emb,
                    const float* __restrict__ proto,
                    char* __restrict__ ws)
{
    int gid = blockIdx.x * 256 + threadIdx.x;
    if (gid < 131072) {
        int c = gid;
        int strip = c >> 7, r = c & 127;
        int kk = r >> 6, lane = r & 63;
        int row = strip * 16 + (lane & 15);
        int k0  = kk * 32 + (lane >> 4) * 8;
        const float* src = emb + (size_t)row * DIM + k0;
        f32x4 a = *reinterpret_cast<const f32x4*>(src);
        f32x4 b = *reinterpret_cast<const f32x4*>(src + 4);
        bf16x8 v;
        v[0]=(__bf16)a.x; v[1]=(__bf16)a.y; v[2]=(__bf16)a.z; v[3]=(__bf16)a.w;
        v[4]=(__bf16)b.x; v[5]=(__bf16)b.y; v[6]=(__bf16)b.z; v[7]=(__bf16)b.w;
        *reinterpret_cast<bf16x8*>(ws + WS_EMB + (size_t)c * 16) = v;
    } else if (gid < 163840) {
        int c = gid - 131072;
        int nt = c >> 10, within = c & 1023;        // 128-row tiles
        int e0  = within * 8;
        int row = e0 >> 6;
        int k0  = (e0 & 63) ^ ((row & 7) << 3);
        const float* src = proto + (size_t)(nt * 128 + row) * DIM + k0;
        f32x4 a = *reinterpret_cast<const f32x4*>(src);
        f32x4 b = *reinterpret_cast<const f32x4*>(src + 4);
        bf16x8 v;
        v[0]=(__bf16)a.x; v[1]=(__bf16)a.y; v[2]=(__bf16)a.z; v[3]=(__bf16)a.w;
        v[4]=(__bf16)b.x; v[5]=(__bf16)b.y; v[6]=(__bf16)b.z; v[7]=(__bf16)b.w;
        *reinterpret_cast<bf16x8*>(ws + WS_PROTO + (size_t)c * 16) = v;
    } else if (gid < 180224) {
        int r = gid - 163840;
        const f32x4* src = reinterpret_cast<const f32x4*>(emb + (size_t)r * DIM);
        float s = 0.0f;
        #pragma unroll
        for (int i = 0; i < 16; ++i) {
            f32x4 v = src[i];
            s += v.x*v.x + v.y*v.y + v.z*v.z + v.w*v.w;
        }
        reinterpret_cast<float*>(ws + WS_X2)[r]   = s;
        reinterpret_cast<float*>(ws + WS_CROW)[r] = 2.0f * __builtin_amdgcn_rcpf(1.0f - s);
    } else if (gid < 184320) {
        int r = gid - 180224;
        const f32x4* src = reinterpret_cast<const f32x4*>(proto + (size_t)r * DIM);
        float s = 0.0f;
        #pragma unroll
        for (int i = 0; i < 16; ++i) {
            f32x4 v = src[i];
            s += v.x*v.x + v.y*v.y + v.z*v.z + v.w*v.w;
        }
        reinterpret_cast<float*>(ws + WS_P2)[r] = s;
        reinterpret_cast<float*>(ws + WS_RP)[r] = __builtin_amdgcn_rcpf(1.0f - s);
    }
}

// ---------------- main kernel ----------------
// Grid 512 = 64 m-tiles x 8 n-bands; band = bid&7 -> one band per XCD.
// 4 waves; wave owns 64 emb rows x the full 512-proto band.
__global__ __launch_bounds__(256, 2)
void poincare_pairwise_kernel(const char* __restrict__ ws,
                              float* __restrict__ out)
{
    __shared__ __bf16 Bs[4][128 * DIM];   // 64 KiB: 4 proto tile images

    const int tid  = threadIdx.x;
    const int bid  = blockIdx.x;
    const int band = bid & 7;             // n-band -> XCD
    const int mt   = bid >> 3;            // 0..63
    const int m0   = mt * TM;
    const int n0   = band * TNB;

    // ---------- stage proto band (4 tiles, pure linear uint4 copy) ----------
    {
        const uint4* psrc = reinterpret_cast<const uint4*>(ws + WS_PROTO + (size_t)(band * 4) * 16384);
        uint4* pdst = reinterpret_cast<uint4*>(&Bs[0][0]);
        #pragma unroll
        for (int i = 0; i < 16; ++i)
            pdst[i * 256 + tid] = psrc[i * 256 + tid];
    }

    const int lane = tid & 63;
    const int wid  = tid >> 6;            // wave -> 64-row emb strip
    const int lr   = lane & 15;
    const int g    = lane >> 4;
    const int lk   = g * 8;

    // ---------- emb fragments: direct per-wave loads (no LDS) ----------
    // strip = 16 rows; wave's rf block -> strip mt*16 + wid*4 + rf.
    bf16x8 xfrag[4][2];                   // [rf][kk]
    const bf16x8* ebase = reinterpret_cast<const bf16x8*>(ws + WS_EMB);
    #pragma unroll
    for (int rf = 0; rf < 4; ++rf) {
        size_t sb = (size_t)(mt * 16 + wid * 4 + rf) * 128 + lane;
        xfrag[rf][0] = ebase[sb];
        xfrag[rf][1] = ebase[sb + 64];
    }

    // per-lane row params
    float  x2[4], crow[4];
    float* rowp[4];
    #pragma unroll
    for (int rf = 0; rf < 4; ++rf) {
        int xrow = wid * 64 + rf * 16 + lr;
        x2[rf]   = reinterpret_cast<const float*>(ws + WS_X2)[m0 + xrow];
        crow[rf] = reinterpret_cast<const float*>(ws + WS_CROW)[m0 + xrow];
        rowp[rf] = out + (size_t)(m0 + xrow) * NCON + n0;
    }
    const float* p2a = reinterpret_cast<const float*>(ws + WS_P2) + n0;
    const float* rpa = reinterpret_cast<const float*>(ws + WS_RP) + n0;

    __syncthreads();   // the ONLY barrier; stores flow freely hereafter

    // ---------- 4 proto tiles: MFMA + epilogue + store, NO barriers ----------
    for (int t = 0; t < 4; ++t) {
        f32x4 acc[4][8] = {};             // [rf][pf]
        #pragma unroll
        for (int kk = 0; kk < 2; ++kk) {
            bf16x8 pfrag[8];
            #pragma unroll
            for (int pf = 0; pf < 8; ++pf) {
                int prow = pf * 16 + lr;
                int kep  = (kk * 32 + lk) ^ ((prow & 7) << 3);
                pfrag[pf] = *reinterpret_cast<const bf16x8*>(&Bs[t][prow * DIM + kep]);
            }
            #pragma unroll
            for (int pf = 0; pf < 8; ++pf)
                #pragma unroll
                for (int rf = 0; rf < 4; ++rf)
                    acc[rf][pf] = __builtin_amdgcn_mfma_f32_16x16x32_bf16(
                        pfrag[pf], xfrag[rf][kk], acc[rf][pf], 0, 0, 0);
        }

        // epilogue: poly acosh + store.
        // D layout: col = lane&15 -> emb row (lr); row = g*4+j -> proto idx.
        const int cb = t * 128;
        #pragma unroll
        for (int pf = 0; pf < 8; ++pf) {
            int   col = cb + pf * 16 + g * 4;
            f32x4 p2  = *reinterpret_cast<const f32x4*>(p2a + col);
            f32x4 rp  = *reinterpret_cast<const f32x4*>(rpa + col);
            #pragma unroll
            for (int rf = 0; rf < 4; ++rf) {
                f32x4 dv;
                #pragma unroll
                for (int j = 0; j < 4; ++j) {
                    float sq = fmaxf(x2[rf] + p2[j] - 2.0f * acc[rf][pf][j], 0.0f);
                    float tt = sq * (crow[rf] * rp[j]);
                    float u  = __builtin_amdgcn_sqrtf(tt);
                    float pl = fmaf(fmaf(fmaf(-0.0013415f, tt, 0.0164700f),
                                         tt, -0.1113059f),
                                    tt, 1.4134377f);
                    dv[j]    = u * pl;
                }
                *reinterpret_cast<f32x4*>(rowp[rf] + col) = dv;
            }
        }
    }
}

extern "C" void kernel_launch(void* const* d_in, const int* in_sizes, int n_in,
                              void* d_out, int out_size, void* d_ws, size_t ws_size,
                              hipStream_t stream) {
    const float* emb   = (const float*)d_in[0];
    const float* proto = (const float*)d_in[1];
    float* out = (float*)d_out;
    char* ws   = (char*)d_ws;

    prepass_kernel<<<720, 256, 0, stream>>>(emb, proto, ws);   // 184320 threads
    poincare_pairwise_kernel<<<512, 256, 0, stream>>>(ws, out); // 64 m x 8 bands
}